// Round 4
// baseline (175.332 us; speedup 1.0000x reference)
//
#include <hip/hip_runtime.h>
#include <cfloat>

#define NPTS 16384
#define C_CHUNKS 32
#define CHUNK (NPTS / C_CHUNKS)    // 512 B-points per block
#define NA 4                        // A-points per thread
#define NBLOCKS (2 * C_CHUNKS * NPTS / (256 * NA))   // 2*32*16 = 1024
#define CTR_INIT 0x7F7F7F7Fu

typedef float v2f __attribute__((ext_vector_type(2)));

// minsq[0 .. 2*NPTS-1] : per-A-point running min (float bits, signed-int ordered)
// minsq[2*NPTS]        : completion counter (starts at 0x7F7F7F7F from memset)
__global__ __launch_bounds__(256) void chamfer_kernel(
    const float* __restrict__ target, const float* __restrict__ output,
    int* __restrict__ minsq, float* __restrict__ out)
{
    __shared__ float bsx[CHUNK], bsy[CHUNK], bsz[CHUNK], bsw[CHUNK];

    const int dir = blockIdx.z;
    const float* __restrict__ A = dir ? target : output;
    const float* __restrict__ B = dir ? output : target;

    // stage + pack this B chunk in SoA: (-2bx, -2by, -2bz, |b|^2)
    const int j0 = blockIdx.y * CHUNK;
    for (int k = threadIdx.x; k < CHUNK; k += 256) {
        int j = j0 + k;
        float x = B[3 * j], y = B[3 * j + 1], z = B[3 * j + 2];
        bsx[k] = -2.f * x; bsy[k] = -2.f * y; bsz[k] = -2.f * z;
        bsw[k] = fmaf(x, x, fmaf(y, y, z * z));
    }

    const int i0 = blockIdx.x * (256 * NA) + threadIdx.x;
    v2f ax[NA], ay[NA], az[NA];
    float sqa[NA], m[NA];
    #pragma unroll
    for (int k = 0; k < NA; ++k) {
        int i = i0 + k * 256;
        float x = A[3 * i], y = A[3 * i + 1], z = A[3 * i + 2];
        ax[k] = (v2f){x, x}; ay[k] = (v2f){y, y}; az[k] = (v2f){z, z};
        sqa[k] = fmaf(x, x, fmaf(y, y, z * z));
        m[k] = FLT_MAX;
    }
    __syncthreads();

    // 2 B-points per step: 3 v_pk_fma_f32 + 1 v_min3_f32 per A-point = 2 instr/pair
    #pragma unroll 2
    for (int j = 0; j < CHUNK; j += 2) {
        v2f px = *(const v2f*)&bsx[j];   // wave-uniform ds_read_b64 broadcasts
        v2f py = *(const v2f*)&bsy[j];
        v2f pz = *(const v2f*)&bsz[j];
        v2f pw = *(const v2f*)&bsw[j];
        #pragma unroll
        for (int k = 0; k < NA; ++k) {
            v2f s = __builtin_elementwise_fma(ax[k], px,
                      __builtin_elementwise_fma(ay[k], py,
                        __builtin_elementwise_fma(az[k], pz, pw)));
            m[k] = fminf(m[k], fminf(s.x, s.y));   // -> v_min3_f32
        }
    }

    // min_j d^2 = sqa + min_j(-2 a.b + |b|^2); signed-int compare on float bits
    // orders correctly incl. tiny negative rounding results
    #pragma unroll
    for (int k = 0; k < NA; ++k)
        atomicMin(&minsq[dir * NPTS + i0 + k * 256], __float_as_int(m[k] + sqa[k]));

    // ---- last block finalizes: sqrt-sum over all mins, write out ----
    __threadfence();
    __shared__ bool amLast;
    if (threadIdx.x == 0) {
        unsigned old = atomicAdd((unsigned*)&minsq[2 * NPTS], 1u);
        amLast = (old == CTR_INIT + NBLOCKS - 1);
    }
    __syncthreads();
    if (amLast) {
        __threadfence();
        float s = 0.f;
        for (int k = threadIdx.x; k < 2 * NPTS; k += 256) {
            int v = __hip_atomic_load(&minsq[k], __ATOMIC_RELAXED,
                                      __HIP_MEMORY_SCOPE_AGENT);
            s += sqrtf(fmaxf(__int_as_float(v), 0.f));
        }
        for (int off = 32; off; off >>= 1) s += __shfl_down(s, off, 64);
        __shared__ float partial[4];
        if ((threadIdx.x & 63) == 0) partial[threadIdx.x >> 6] = s;
        __syncthreads();
        if (threadIdx.x == 0)
            out[0] = (partial[0] + partial[1] + partial[2] + partial[3]) * 0.001f;
    }
}

extern "C" void kernel_launch(void* const* d_in, const int* in_sizes, int n_in,
                              void* d_out, int out_size, void* d_ws, size_t ws_size,
                              hipStream_t stream) {
    const float* target = (const float*)d_in[0];  // [16384,3]
    const float* output = (const float*)d_in[1];  // [16384,3]
    float* out = (float*)d_out;
    int* minsq = (int*)d_ws;                      // 2*NPTS mins + 1 counter

    // 0x7F bytes -> mins start at 0x7F7F7F7F (huge float, valid signed order),
    // counter starts at CTR_INIT
    hipMemsetAsync(minsq, 0x7F, (2 * NPTS + 1) * sizeof(int), stream);

    chamfer_kernel<<<dim3(NPTS / (256 * NA), C_CHUNKS, 2), 256, 0, stream>>>(
        target, output, minsq, out);
}

// Round 5
// 149.299 us; speedup vs baseline: 1.1744x; 1.1744x over previous
//
#include <hip/hip_runtime.h>
#include <cfloat>

#define NPTS 16384
#define C_CHUNKS 32
#define CHUNK (NPTS / C_CHUNKS)    // 512 B-points per block, pair-packed = 8 KB LDS
#define NA 8                        // A-points per thread
#define NBLOCKS (2 * C_CHUNKS * NPTS / (256 * NA))   // 2*32*8 = 512
#define CTR_INIT 0x7F7F7F7Fu

typedef float v2f __attribute__((ext_vector_type(2)));

// minsq[0 .. 2*NPTS-1] : per-A-point running min (float bits, signed-int ordered)
// minsq[2*NPTS]        : completion counter (starts at CTR_INIT from memset)
__global__ __launch_bounds__(256) void chamfer_kernel(
    const float* __restrict__ target, const float* __restrict__ output,
    int* __restrict__ minsq, float* __restrict__ out)
{
    // pair-packed: bs[2m] = (-2x0,-2x1,-2y0,-2y1), bs[2m+1] = (-2z0,-2z1,w0,w1)
    __shared__ float4 bs[CHUNK];

    const int dir = blockIdx.z;
    const float* __restrict__ A = dir ? target : output;
    const float* __restrict__ B = dir ? output : target;

    const int j0 = blockIdx.y * CHUNK;
    // 256 threads, 256 pairs: one pair each
    {
        int mI = threadIdx.x;
        int j = j0 + 2 * mI;
        float x0 = B[3 * j + 0], y0 = B[3 * j + 1], z0 = B[3 * j + 2];
        float x1 = B[3 * j + 3], y1 = B[3 * j + 4], z1 = B[3 * j + 5];
        bs[2 * mI + 0] = make_float4(-2.f * x0, -2.f * x1, -2.f * y0, -2.f * y1);
        bs[2 * mI + 1] = make_float4(-2.f * z0, -2.f * z1,
                                     fmaf(x0, x0, fmaf(y0, y0, z0 * z0)),
                                     fmaf(x1, x1, fmaf(y1, y1, z1 * z1)));
    }

    const int i0 = blockIdx.x * (256 * NA) + threadIdx.x;
    v2f ax[NA], ay[NA], az[NA];
    float sqa[NA], m[NA];
    #pragma unroll
    for (int k = 0; k < NA; ++k) {
        int i = i0 + k * 256;
        float x = A[3 * i], y = A[3 * i + 1], z = A[3 * i + 2];
        ax[k] = (v2f){x, x}; ay[k] = (v2f){y, y}; az[k] = (v2f){z, z};
        sqa[k] = fmaf(x, x, fmaf(y, y, z * z));
        m[k] = FLT_MAX;
    }
    __syncthreads();

    // per 2 B-points: 2 ds_read_b128 feed NA*4 = 32 VALU instr (16:1 ratio);
    // 3 v_pk_fma_f32 + 1 v_min3_f32 per A-point = 2 instr per (A,B) pair
    #pragma unroll 2
    for (int mi = 0; mi < CHUNK / 2; ++mi) {
        float4 q0 = bs[2 * mi + 0];   // wave-uniform -> LDS broadcast
        float4 q1 = bs[2 * mi + 1];
        v2f px = (v2f){q0.x, q0.y}, py = (v2f){q0.z, q0.w};
        v2f pz = (v2f){q1.x, q1.y}, pw = (v2f){q1.z, q1.w};
        #pragma unroll
        for (int k = 0; k < NA; ++k) {
            v2f s = __builtin_elementwise_fma(ax[k], px,
                      __builtin_elementwise_fma(ay[k], py,
                        __builtin_elementwise_fma(az[k], pz, pw)));
            m[k] = fminf(m[k], fminf(s.x, s.y));   // -> v_min3_f32
        }
    }

    // min_j d^2 = sqa + min_j(-2 a.b + |b|^2); signed-int compare on float bits
    #pragma unroll
    for (int k = 0; k < NA; ++k)
        atomicMin(&minsq[dir * NPTS + i0 + k * 256], __float_as_int(m[k] + sqa[k]));

    // ---- last block finalizes: sqrt-sum over all mins, write out ----
    __threadfence();
    __shared__ bool amLast;
    if (threadIdx.x == 0) {
        unsigned old = atomicAdd((unsigned*)&minsq[2 * NPTS], 1u);
        amLast = (old == CTR_INIT + NBLOCKS - 1);
    }
    __syncthreads();
    if (amLast) {
        __threadfence();
        float s = 0.f;
        for (int k = threadIdx.x; k < 2 * NPTS; k += 256) {
            int v = __hip_atomic_load(&minsq[k], __ATOMIC_RELAXED,
                                      __HIP_MEMORY_SCOPE_AGENT);
            s += sqrtf(fmaxf(__int_as_float(v), 0.f));
        }
        for (int off = 32; off; off >>= 1) s += __shfl_down(s, off, 64);
        __shared__ float partial[4];
        if ((threadIdx.x & 63) == 0) partial[threadIdx.x >> 6] = s;
        __syncthreads();
        if (threadIdx.x == 0)
            out[0] = (partial[0] + partial[1] + partial[2] + partial[3]) * 0.001f;
    }
}

extern "C" void kernel_launch(void* const* d_in, const int* in_sizes, int n_in,
                              void* d_out, int out_size, void* d_ws, size_t ws_size,
                              hipStream_t stream) {
    const float* target = (const float*)d_in[0];  // [16384,3]
    const float* output = (const float*)d_in[1];  // [16384,3]
    float* out = (float*)d_out;
    int* minsq = (int*)d_ws;                      // 2*NPTS mins + 1 counter

    hipMemsetAsync(minsq, 0x7F, (2 * NPTS + 1) * sizeof(int), stream);

    chamfer_kernel<<<dim3(NPTS / (256 * NA), C_CHUNKS, 2), 256, 0, stream>>>(
        target, output, minsq, out);
}